// Round 1
// baseline (539.407 us; speedup 1.0000x reference)
//
#include <hip/hip_runtime.h>

#define B_TOT 32768
#define NF    64
#define NB    33
#define NSEG  32   // NB-1
#define E     64
#define BPB   256  // b-rows per block

__global__ __launch_bounds__(256) void pwl_kernel(
    const float* __restrict__ X,       // [B, NF]
    const float* __restrict__ bounds,  // [NF, NB]
    const float* __restrict__ W,       // [NF, NSEG, E]
    const float* __restrict__ bias,    // [NF, E]
    float* __restrict__ out)           // [B, NF*E]
{
    // Interleaved record per (j, e-pair): {P[j][2e2], P[j][2e2+1], W[j][2e2], W[j][2e2+1]}
    // One conflict-free ds_read_b128 per row-half in phase B.
    __shared__ __align__(16) float4 sPW[NSEG][E / 2];  // 16 KB
    __shared__ float sBounds[NB];
    __shared__ uint2 sJF[BPB];                         // 2 KB  {j, frac-bits}

    const int f   = blockIdx.x;        // f fastest -> same-b0 blocks share X cache lines
    const int tid = threadIdx.x;
    const int b0  = blockIdx.y * BPB;

    // ---- issue long-latency global loads early (hidden under W staging) ----
    const float x = X[(size_t)(b0 + tid) * NF + f];          // strided gather, L2/L3-served
    float biasv = 0.0f;
    if (tid < E) biasv = bias[f * E + tid];

    // ---- stage W[f] directly into sPW .zw slots ----
    {
        // global float2 idx covers W[f] floats [2*idx, 2*idx+1]
        //   -> j = idx>>5, e2 = idx&31 -> flat float4 slot j*32+e2 == idx
        const float2* Wg  = reinterpret_cast<const float2*>(W + f * (NSEG * E));
        float*        flat = &sPW[0][0].x;
        #pragma unroll
        for (int t = 0; t < 4; ++t) {
            const int idx = tid + t * 256;
            const float2 w2 = Wg[idx];                        // 512 B contiguous per wave
            *reinterpret_cast<float2*>(flat + idx * 4 + 2) = w2;  // .zw
        }
        if (tid < NB) sBounds[tid] = bounds[f * NB + tid];
    }
    __syncthreads();

    // ---- phase A: bucket one x per thread ----
    {
        int c = 0;
        #pragma unroll
        for (int i = 0; i < NB; ++i) c += (sBounds[i] <= x) ? 1 : 0;
        int j = c - 1;
        j = (j < 0) ? 0 : ((j > NSEG - 1) ? NSEG - 1 : j);
        const float lo = sBounds[j];
        const float hi = sBounds[j + 1];
        float fr = (x - lo) / (hi - lo);
        fr = fminf(fmaxf(fr, 0.0f), 1.0f);
        sJF[tid] = make_uint2((unsigned)j, __float_as_uint(fr));
    }

    // ---- prefix sums into sPW .xy: P[j][e] = bias[e] + sum_{i<j} W[i][e] ----
    if (tid < E) {
        const int e2 = tid >> 1;
        const int c  = tid & 1;
        float acc = biasv;
        float* flat = &sPW[0][0].x;
        #pragma unroll
        for (int i = 0; i < NSEG; ++i) {
            float* cell = flat + (i * 32 + e2) * 4;   // cell owned exclusively by this tid
            const float w = cell[2 + c];
            cell[c] = acc;
            acc += w;
        }
    }
    __syncthreads();

    // ---- phase B: 32 lanes per b-row, float2 per lane ----
    // Wave = 2 rows/iter: 2 j-windows (2-way LDS aliasing = free),
    // store = 2 x 256 B fully contiguous segments.
    const int lane  = tid & 63;
    const int wv    = tid >> 6;        // wave 0..3
    const int half  = lane >> 5;       // row parity within wave
    const int e2    = lane & 31;       // e-pair: e = 2*e2
    const int wbase = wv * 64;         // this wave owns rows [wbase, wbase+64)

    const float4* __restrict__ PW = &sPW[0][0];
    float2* outp = reinterpret_cast<float2*>(
        out + (size_t)(b0 + wbase + half) * (NF * E) + f * E + 2 * e2);

    #pragma unroll 8
    for (int it = 0; it < 32; ++it) {
        const uint2 jf = sJF[wbase + 2 * it + half];  // broadcast (2 addrs/wave)
        const int   j  = (int)jf.x;
        const float fr = __uint_as_float(jf.y);
        const float4 v = PW[j * 32 + e2];             // b128, conflict-free per half
        float2 r;
        r.x = fmaxf(fmaf(fr, v.z, v.x), 0.0f);
        r.y = fmaxf(fmaf(fr, v.w, v.y), 0.0f);
        *outp = r;
        outp += 4096;                                 // 2 rows * NF*E floats / 2
    }
}

extern "C" void kernel_launch(void* const* d_in, const int* in_sizes, int n_in,
                              void* d_out, int out_size, void* d_ws, size_t ws_size,
                              hipStream_t stream) {
    const float* X      = (const float*)d_in[0];
    const float* bounds = (const float*)d_in[1];
    const float* W      = (const float*)d_in[2];
    const float* bias   = (const float*)d_in[3];
    float* out          = (float*)d_out;

    dim3 grid(NF, B_TOT / BPB);   // (64, 128)
    dim3 block(256);
    pwl_kernel<<<grid, block, 0, stream>>>(X, bounds, W, bias, out);
}